// Round 17
// baseline (163.116 us; speedup 1.0000x reference)
//
#include <hip/hip_runtime.h>
#include <hip/hip_bf16.h>
#include <cstddef>

// GCN forward: out = A·(relu(A·(X·W1)+b1))·W2 + b2
// NFEAT=512, NHID=128, NCLS=40 hard-wired; N,E from in_sizes.
// R17: gemm1 double-buffered LDS (BK=32, 30KB, 5 blocks/CU), 1 barrier/iter,
// 3-set register prefetch ring with loads issued 2 iterations ahead.
// Else identical to R16.

typedef float f32x4 __attribute__((ext_vector_type(4)));
typedef short bf16x8 __attribute__((ext_vector_type(8)));

static __device__ __forceinline__ short f2bf(float f) {
    __hip_bfloat16 b = __float2bfloat16(f);
    return *reinterpret_cast<short*>(&b);
}
static __device__ __forceinline__ float bflo(unsigned u) {
    union { unsigned i; float f; } v; v.i = u << 16; return v.f;
}
static __device__ __forceinline__ float bfhi(unsigned u) {
    union { unsigned i; float f; } v; v.i = u & 0xFFFF0000u; return v.f;
}
static __device__ __forceinline__ unsigned pack2bf(float lo, float hi) {
    unsigned a = (unsigned short)f2bf(lo);
    unsigned b = (unsigned short)f2bf(hi);
    return a | (b << 16);
}
static __device__ __forceinline__ uint2 cvt4(float4 v) {
    return make_uint2(pack2bf(v.x, v.y), pack2bf(v.z, v.w));
}

typedef const __attribute__((address_space(1))) void* gas_ptr;
typedef __attribute__((address_space(3))) void* las_ptr;
static __device__ __forceinline__ void gload16(const void* g, void* l) {
    __builtin_amdgcn_global_load_lds((gas_ptr)g, (las_ptr)l, 16, 0, 0);
}

// ---- prep: W1->W1Tb (plain bf16 W1T [128][512]), W2->W2Ts (swizzled), zero cur ----
__global__ __launch_bounds__(256) void prep_kernel(
    const float* __restrict__ W1, short* __restrict__ W1Tb,
    const float* __restrict__ W2, short* __restrict__ W2Ts,
    int* __restrict__ cur, int N)
{
    int idx = blockIdx.x * 256 + threadIdx.x;
    if (idx < 65536) {
        int k = idx >> 7, n = idx & 127;
        W1Tb[n * 512 + k] = f2bf(W1[idx]);
    } else if (idx < 65536 + 6144) {
        int i2 = idx - 65536;
        int n = i2 >> 7, k = i2 & 127;
        W2Ts[i2 ^ ((n & 7) << 3)] = (n < 40) ? f2bf(W2[k * 40 + n]) : (short)0;
    } else if (idx < 65536 + 6144 + N) {
        cur[idx - 65536 - 6144] = 0;
    }
}

// ---------------- CSR build ----------------
__global__ __launch_bounds__(256) void hist_kernel(const int* __restrict__ row,
                                                   int* __restrict__ counts, int E)
{
    int e = blockIdx.x * 256 + threadIdx.x;
    if (e < E) atomicAdd(&counts[row[e]], 1);
}

__global__ __launch_bounds__(256) void scan1_kernel(const int* __restrict__ counts,
                                                    int* __restrict__ excl,
                                                    int* __restrict__ bsum, int N)
{
    __shared__ int s[256];
    const int t = threadIdx.x;
    const int i = blockIdx.x * 256 + t;
    int v = (i < N) ? counts[i] : 0;
    s[t] = v; __syncthreads();
#pragma unroll
    for (int off = 1; off < 256; off <<= 1) {
        int tmp = (t >= off) ? s[t - off] : 0;
        __syncthreads();
        s[t] += tmp;
        __syncthreads();
    }
    if (i < N) excl[i] = s[t] - v;
    if (t == 255) bsum[blockIdx.x] = s[255];
}

// merged scan2+scan3: each block scans bsum in LDS, applies its own prefix
__global__ __launch_bounds__(256) void scan23_kernel(int* __restrict__ rowptr,
                                                     const int* __restrict__ bsum,
                                                     int* __restrict__ cur,
                                                     int N, int E, int NB)
{
    __shared__ int s[256];
    const int t = threadIdx.x;
    int v = (t < NB) ? bsum[t] : 0;
    s[t] = v; __syncthreads();
#pragma unroll
    for (int off = 1; off < 256; off <<= 1) {
        int tmp = (t >= off) ? s[t - off] : 0;
        __syncthreads();
        s[t] += tmp;
        __syncthreads();
    }
    const int add = (blockIdx.x > 0) ? s[blockIdx.x - 1] : 0;  // exclusive prefix
    const int i = blockIdx.x * 256 + t;
    if (i < N) {
        int v2 = rowptr[i] + add;
        rowptr[i] = v2;
        cur[i] = v2;
    }
    if (i == 0) rowptr[N] = E;
}

// ---------------- merged: gemm1 (blocks [0,G1)) + sortedges (blocks [G1,..)) ----------------
// gemm1: XW1b[M,128](bf16) = X[M,512](f32) @ W1. 64x128 tile, BK=32.
// Double-buffered LDS (30KB, 5 blocks/CU), 1 barrier/iter, loads 2 iters ahead.
__global__ __launch_bounds__(256, 5) void gemm1_sort_kernel(
    const float* __restrict__ X, const short* __restrict__ W1Tb,
    short* __restrict__ XW1b, int M, int G1,
    const int* __restrict__ erow, const int* __restrict__ ecol,
    const float* __restrict__ ew, int* __restrict__ cur,
    int2* __restrict__ se, int E)
{
    __shared__ __align__(16) short As[2][64 * 40];    // 2 x 5 KB (pitch 40 = 80B, 2-way free)
    __shared__ __align__(16) short Bs[2][128 * 40];   // 2 x 10 KB

    const int tid = threadIdx.x;

    if (blockIdx.x >= G1) {
        // ---- sortedges body ----
        int e = (blockIdx.x - G1) * 256 + tid;
        if (e < E) {
            int r = erow[e];
            int pos = atomicAdd(&cur[r], 1);
            se[pos] = make_int2(ecol[e], __float_as_int(ew[e]));
        }
        return;
    }

    // ---- gemm1 body ----
    const int w   = tid >> 6;
    const int l   = tid & 63;
    const int l15 = l & 15;
    const int l4  = l >> 4;
    const int row0 = blockIdx.x * 64;
    const int rb   = (w & 1) * 32;
    const int cb   = (w >> 1) * 64;

    // coalesced staging indices (BK=32):
    // A: rows arow / 32+arow, f32 cols acol..acol+3 (8 lanes cover 128B of a row)
    const int arow = tid >> 3;               // 0..31
    const int acol = (tid & 7) * 4;          // f32 col
    const int ar0 = row0 + arow,      ac0 = ar0 < M ? ar0 : M - 1;
    const int ar1 = row0 + 32 + arow, ac1 = ar1 < M ? ar1 : M - 1;
    const float* ap0 = X + (size_t)ac0 * 512 + acol;
    const float* ap1 = X + (size_t)ac1 * 512 + acol;
    // B: rows brow / 64+brow, bf16 cols bcol..bcol+7 (4 lanes cover 64B of a row)
    const int brow = tid >> 2;               // 0..63
    const int bcol = (tid & 3) * 8;          // bf16 col
    const short* bp0 = W1Tb + (size_t)brow * 512 + bcol;
    const short* bp1 = W1Tb + (size_t)(64 + brow) * 512 + bcol;

    f32x4 acc[2][4];
#pragma unroll
    for (int i = 0; i < 2; ++i)
#pragma unroll
        for (int f = 0; f < 4; ++f) acc[i][f] = (f32x4)0.f;

    // 3-set register prefetch ring (statically indexed under full unroll)
    float4 pa[3][2];
    bf16x8 pb[3][2];

#define LOADSET(s, kt)                                              \
    do {                                                            \
        pa[s][0] = *(const float4*)(ap0 + (kt) * 32);               \
        pa[s][1] = *(const float4*)(ap1 + (kt) * 32);               \
        pb[s][0] = *(const bf16x8*)(bp0 + (kt) * 32);               \
        pb[s][1] = *(const bf16x8*)(bp1 + (kt) * 32);               \
    } while (0)

#define WRITESET(buf, s)                                            \
    do {                                                            \
        *(uint2*)&As[buf][arow * 40 + acol]        = cvt4(pa[s][0]);\
        *(uint2*)&As[buf][(32 + arow) * 40 + acol] = cvt4(pa[s][1]);\
        *(bf16x8*)&Bs[buf][brow * 40 + bcol]       = pb[s][0];      \
        *(bf16x8*)&Bs[buf][(64 + brow) * 40 + bcol] = pb[s][1];     \
    } while (0)

    // prologue: regs 0,1,2 in flight; buf0 written from set0
    LOADSET(0, 0);
    LOADSET(1, 1);
    LOADSET(2, 2);
    WRITESET(0, 0);
    __syncthreads();

#pragma unroll
    for (int kt = 0; kt < 16; ++kt) {
        if (kt + 1 < 16) WRITESET((kt + 1) & 1, (kt + 1) % 3);  // regs[kt+1], issued 2 iters ago
        if (kt + 3 < 16) LOADSET(kt % 3, kt + 3);               // refill freed set
        // compute buf[kt&1]
        {
            const int b = kt & 1;
            bf16x8 af0 = *(const bf16x8*)&As[b][(rb + l15) * 40 + l4 * 8];
            bf16x8 af1 = *(const bf16x8*)&As[b][(rb + 16 + l15) * 40 + l4 * 8];
#pragma unroll
            for (int f = 0; f < 4; ++f) {
                const bf16x8 bf_ = *(const bf16x8*)&Bs[b][(cb + f * 16 + l15) * 40 + l4 * 8];
                acc[0][f] = __builtin_amdgcn_mfma_f32_16x16x32_bf16(af0, bf_, acc[0][f], 0, 0, 0);
                acc[1][f] = __builtin_amdgcn_mfma_f32_16x16x32_bf16(af1, bf_, acc[1][f], 0, 0, 0);
            }
        }
        __syncthreads();
    }
#undef LOADSET
#undef WRITESET

#pragma unroll
    for (int i = 0; i < 2; ++i)
#pragma unroll
        for (int r = 0; r < 4; ++r) {
            const int row = row0 + rb + i * 16 + l4 * 4 + r;
            if (row < M) {
#pragma unroll
                for (int f = 0; f < 4; ++f)
                    XW1b[(size_t)row * 128 + cb + f * 16 + l15] = f2bf(acc[i][f][r]);
            }
        }
}

// ---- fused segment1+gemm2: h48[r] = bf16(relu(b1 + Σ w_j xw1b[col_j])) @ W2 ----
__global__ __launch_bounds__(256) void seg1g2_kernel(
    const int* __restrict__ rowptr, const int2* __restrict__ se,
    const uint4* __restrict__ x4, const float* __restrict__ b1,
    const short* __restrict__ W2Ts, unsigned short* __restrict__ h48, int N)
{
    __shared__ __align__(16) short Ws[48 * 128];   // 12 KB, pre-swizzled
    __shared__ __align__(16) short Hs[16 * 136];   // 4.25 KB, pitch 136

    const int tid  = threadIdx.x;
    const int w    = tid >> 6;
    const int lane = tid & 63;
    const int qt   = lane >> 4;
    const int ql   = lane & 15;
    const int row0q = blockIdx.x * 4;
    const int r  = row0q + w;
    const int rc = r < N ? r : N - 1;     // clamp: all waves reach the barrier

    {
        const char* src = (const char*)W2Ts;
        char* dst = (char*)Ws;
#pragma unroll
        for (int i = 0; i < 3; ++i)
            gload16(src + i * 4096 + tid * 16, dst + i * 4096 + tid * 16);
    }

    float acc[8];
    if (qt == 0) {
        const float4 ba = *(const float4*)(b1 + 8 * ql);
        const float4 bb = *(const float4*)(b1 + 8 * ql + 4);
        acc[0]=ba.x; acc[1]=ba.y; acc[2]=ba.z; acc[3]=ba.w;
        acc[4]=bb.x; acc[5]=bb.y; acc[6]=bb.z; acc[7]=bb.w;
    } else {
#pragma unroll
        for (int i = 0; i < 8; ++i) acc[i] = 0.f;
    }

    int j = rowptr[rc];
    const int end = rowptr[rc + 1];
    for (; j + 7 < end; j += 8) {
        const int2 ea = se[j + qt];
        const int2 eb = se[j + 4 + qt];
        const uint4 ua = x4[(size_t)ea.x * 16 + ql];
        const uint4 ub = x4[(size_t)eb.x * 16 + ql];
        const float wa = __int_as_float(ea.y), wb = __int_as_float(eb.y);
        acc[0] = fmaf(wa, bflo(ua.x), acc[0]); acc[1] = fmaf(wa, bfhi(ua.x), acc[1]);
        acc[2] = fmaf(wa, bflo(ua.y), acc[2]); acc[3] = fmaf(wa, bfhi(ua.y), acc[3]);
        acc[4] = fmaf(wa, bflo(ua.z), acc[4]); acc[5] = fmaf(wa, bfhi(ua.z), acc[5]);
        acc[6] = fmaf(wa, bflo(ua.w), acc[6]); acc[7] = fmaf(wa, bfhi(ua.w), acc[7]);
        acc[0] = fmaf(wb, bflo(ub.x), acc[0]); acc[1] = fmaf(wb, bfhi(ub.x), acc[1]);
        acc[2] = fmaf(wb, bflo(ub.y), acc[2]); acc[3] = fmaf(wb, bfhi(ub.y), acc[3]);
        acc[4] = fmaf(wb, bflo(ub.z), acc[4]); acc[5] = fmaf(wb, bfhi(ub.z), acc[5]);
        acc[6] = fmaf(wb, bflo(ub.w), acc[6]); acc[7] = fmaf(wb, bfhi(ub.w), acc[7]);
    }
    for (; j < end; j += 4) {
        const int idx = j + qt;
        const int ic  = idx < end ? idx : end - 1;
        const int2 e  = se[ic];
        const float wt = idx < end ? __int_as_float(e.y) : 0.f;
        const uint4 u = x4[(size_t)e.x * 16 + ql];
        acc[0] = fmaf(wt, bflo(u.x), acc[0]); acc[1] = fmaf(wt, bfhi(u.x), acc[1]);
        acc[2] = fmaf(wt, bflo(u.y), acc[2]); acc[3] = fmaf(wt, bfhi(u.y), acc[3]);
        acc[4] = fmaf(wt, bflo(u.z), acc[4]); acc[5] = fmaf(wt, bfhi(u.z), acc[5]);
        acc[6] = fmaf(wt, bflo(u.w), acc[6]); acc[7] = fmaf(wt, bfhi(u.w), acc[7]);
    }
#pragma unroll
    for (int i = 0; i < 8; ++i) {
        acc[i] += __shfl_xor(acc[i], 16);
        acc[i] += __shfl_xor(acc[i], 32);
    }
    if (qt == 0) {
        uint4 o;
        o.x = pack2bf(fmaxf(acc[0], 0.f), fmaxf(acc[1], 0.f));
        o.y = pack2bf(fmaxf(acc[2], 0.f), fmaxf(acc[3], 0.f));
        o.z = pack2bf(fmaxf(acc[4], 0.f), fmaxf(acc[5], 0.f));
        o.w = pack2bf(fmaxf(acc[6], 0.f), fmaxf(acc[7], 0.f));
        *(uint4*)&Hs[w * 136 + ql * 8] = o;   // h row w (relu'd bf16)
    }
    __syncthreads();   // drains gload16 (vmcnt) + Hs writes

    // MFMA tail on wave 0: D[16,48] = Hs[16,128] @ W2; rows 4..15 garbage, discarded.
    if (tid < 64) {
        const int l15 = lane & 15;
        const int l4  = lane >> 4;
        const int swz = (l15 & 7) << 3;
        f32x4 acc2[3];
#pragma unroll
        for (int f = 0; f < 3; ++f) acc2[f] = (f32x4)0.f;
#pragma unroll
        for (int kt = 0; kt < 4; ++kt) {
            const bf16x8 a = *(const bf16x8*)&Hs[l15 * 136 + kt * 32 + l4 * 8];
#pragma unroll
            for (int f = 0; f < 3; ++f) {
                const int si = ((f * 16 + l15) * 128 + kt * 32 + l4 * 8) ^ swz;
                const bf16x8 b = *(const bf16x8*)&Ws[si];
                acc2[f] = __builtin_amdgcn_mfma_f32_16x16x32_bf16(a, b, acc2[f], 0, 0, 0);
            }
        }
        if (l4 == 0) {
#pragma unroll
            for (int rr = 0; rr < 4; ++rr) {
                const int grow = row0q + rr;
                if (grow < N) {
#pragma unroll
                    for (int f = 0; f < 3; ++f)
                        h48[(size_t)grow * 48 + f * 16 + l15] =
                            (unsigned short)f2bf(acc2[f][rr]);
                }
            }
        }
    }
}

// ---- segment2: out[r] = b2 + sum_j w_j * h48[col_j]  (quarter-wave, 4 edges/instr) ----
__global__ __launch_bounds__(256) void segment2_kernel(
    const int* __restrict__ rowptr, const int2* __restrict__ se,
    const uint2* __restrict__ h48, const float* __restrict__ b2,
    float* __restrict__ out, int N)
{
    const int w    = threadIdx.x >> 6;
    const int lane = threadIdx.x & 63;
    const int qt   = lane >> 4;
    const int ql   = lane & 15;
    const int r = blockIdx.x * 4 + w;
    if (r >= N) return;

    float acc[4];
    if (qt == 0 && ql < 10) {
        const float4 bb = *(const float4*)(b2 + 4 * ql);
        acc[0]=bb.x; acc[1]=bb.y; acc[2]=bb.z; acc[3]=bb.w;
    } else {
#pragma unroll
        for (int i = 0; i < 4; ++i) acc[i] = 0.f;
    }

    int j = rowptr[r];
    const int end = rowptr[r + 1];
    for (; j + 7 < end; j += 8) {
        const int2 ea = se[j + qt];
        const int2 eb = se[j + 4 + qt];
        const uint2 ua = h48[(size_t)ea.x * 12 + ql];
        const uint2 ub = h48[(size_t)eb.x * 12 + ql];
        const float wa = __int_as_float(ea.y), wb = __int_as_float(eb.y);
        acc[0] = fmaf(wa, bflo(ua.x), acc[0]); acc[1] = fmaf(wa, bfhi(ua.x), acc[1]);
        acc[2] = fmaf(wa, bflo(ua.y), acc[2]); acc[3] = fmaf(wa, bfhi(ua.y), acc[3]);
        acc[0] = fmaf(wb, bflo(ub.x), acc[0]); acc[1] = fmaf(wb, bfhi(ub.x), acc[1]);
        acc[2] = fmaf(wb, bflo(ub.y), acc[2]); acc[3] = fmaf(wb, bfhi(ub.y), acc[3]);
    }
    for (; j < end; j += 4) {
        const int idx = j + qt;
        const int ic  = idx < end ? idx : end - 1;
        const int2 e  = se[ic];
        const float wt = idx < end ? __int_as_float(e.y) : 0.f;
        const uint2 u = h48[(size_t)e.x * 12 + ql];
        acc[0] = fmaf(wt, bflo(u.x), acc[0]); acc[1] = fmaf(wt, bfhi(u.x), acc[1]);
        acc[2] = fmaf(wt, bflo(u.y), acc[2]); acc[3] = fmaf(wt, bfhi(u.y), acc[3]);
    }
#pragma unroll
    for (int i = 0; i < 4; ++i) {
        acc[i] += __shfl_xor(acc[i], 16);
        acc[i] += __shfl_xor(acc[i], 32);
    }
    if (qt == 0 && ql < 10) {
        float4 o; o.x = acc[0]; o.y = acc[1]; o.z = acc[2]; o.w = acc[3];
        *(float4*)(out + (size_t)r * 40 + 4 * ql) = o;
    }
}

extern "C" void kernel_launch(void* const* d_in, const int* in_sizes, int n_in,
                              void* d_out, int out_size, void* d_ws, size_t ws_size,
                              hipStream_t stream)
{
    const float* x  = (const float*)d_in[0];
    const int* erow = (const int*)d_in[1];
    const int* ecol = (const int*)d_in[2];
    const float* ew = (const float*)d_in[3];
    const float* w1 = (const float*)d_in[4];
    const float* b1 = (const float*)d_in[5];
    const float* w2 = (const float*)d_in[6];
    const float* b2 = (const float*)d_in[7];
    float* out = (float*)d_out;

    const int N = in_sizes[0] / 512;   // 50000
    const int E = in_sizes[1];         // 800000
    const int NB = (N + 255) / 256;    // 196 (<=256 for scan23)

    // workspace layout (16B-aligned segments)
    short* w1tb = (short*)d_ws;                      // 128*512 bf16 (plain W1T)
    short* w2ts = w1tb + 65536;                      // 48*128 bf16 (swizzled)
    short* xw1b = w2ts + 8192;                       // N*128 bf16 (gather table L1)
    short* h48  = xw1b + (size_t)N * 128;            // N*48 bf16 (gather table L2)
    int* rowptr = (int*)(h48 + (size_t)N * 128);     // N+1 (h48 slot padded to N*128)
    int* cur    = rowptr + (N + 1);                  // N
    int* bsum   = cur + N;                           // 256 (+pad to 8B align)
    int2* se    = (int2*)(bsum + 256 + ((N + 1) & 1)); // E packed edges

    // CSR build + weight prep
    prep_kernel<<<(65536 + 6144 + N + 255) / 256, 256, 0, stream>>>(w1, w1tb, w2, w2ts, cur, N);
    hist_kernel<<<(E + 255) / 256, 256, 0, stream>>>(erow, cur, E);
    scan1_kernel<<<NB, 256, 0, stream>>>(cur, rowptr, bsum, N);
    scan23_kernel<<<NB, 256, 0, stream>>>(rowptr, bsum, cur, N, E, NB);

    // gemm1 + sortedges (independent, merged)
    const int G1 = (N + 63) / 64;
    const int GS = (E + 255) / 256;
    gemm1_sort_kernel<<<G1 + GS, 256, 0, stream>>>(x, w1tb, xw1b, N, G1,
                                                   erow, ecol, ew, cur, se, E);

    // layer 1 aggregate + layer 2 GEMM (fused)
    seg1g2_kernel<<<(N + 3) / 4, 256, 0, stream>>>(rowptr, se,
                                                   (const uint4*)xw1b, b1,
                                                   w2ts, (unsigned short*)h48, N);

    // layer 2 aggregate
    segment2_kernel<<<(N + 3) / 4, 256, 0, stream>>>(rowptr, se,
                                                     (const uint2*)h48, b2, out, N);
}

// Round 18
// 159.335 us; speedup vs baseline: 1.0237x; 1.0237x over previous
//
#include <hip/hip_runtime.h>
#include <hip/hip_bf16.h>
#include <cstddef>

// GCN forward: out = A·(relu(A·(X·W1)+b1))·W2 + b2
// NFEAT=512, NHID=128, NCLS=40 hard-wired; N,E from in_sizes.
// R18: revert R17 (dbuf+ring regressed; compiler sank the ring, VGPR stayed 48).
// gemm1 = R16 config (BK=64, coalesced staging, single-buffer, 27.6KB, 5 blk/CU).
// prep merged into hist (one launch fewer). Else identical to R16.

typedef float f32x4 __attribute__((ext_vector_type(4)));
typedef short bf16x8 __attribute__((ext_vector_type(8)));

static __device__ __forceinline__ short f2bf(float f) {
    __hip_bfloat16 b = __float2bfloat16(f);
    return *reinterpret_cast<short*>(&b);
}
static __device__ __forceinline__ float bflo(unsigned u) {
    union { unsigned i; float f; } v; v.i = u << 16; return v.f;
}
static __device__ __forceinline__ float bfhi(unsigned u) {
    union { unsigned i; float f; } v; v.i = u & 0xFFFF0000u; return v.f;
}
static __device__ __forceinline__ unsigned pack2bf(float lo, float hi) {
    unsigned a = (unsigned short)f2bf(lo);
    unsigned b = (unsigned short)f2bf(hi);
    return a | (b << 16);
}
static __device__ __forceinline__ uint2 cvt4(float4 v) {
    return make_uint2(pack2bf(v.x, v.y), pack2bf(v.z, v.w));
}

typedef const __attribute__((address_space(1))) void* gas_ptr;
typedef __attribute__((address_space(3))) void* las_ptr;
static __device__ __forceinline__ void gload16(const void* g, void* l) {
    __builtin_amdgcn_global_load_lds((gas_ptr)g, (las_ptr)l, 16, 0, 0);
}

// ---- merged prep+hist: weight transposes, zero cur, then edge histogram ----
// blocks [0, PB): prep work (W1T, W2Ts, zero cur). blocks [PB, ..): histogram.
__global__ __launch_bounds__(256) void prep_hist_kernel(
    const float* __restrict__ W1, short* __restrict__ W1Tb,
    const float* __restrict__ W2, short* __restrict__ W2Ts,
    int* __restrict__ cur, int N, int PB,
    const int* __restrict__ erow, int E)
{
    if (blockIdx.x < PB) {
        int idx = blockIdx.x * 256 + threadIdx.x;
        if (idx < 65536) {
            int k = idx >> 7, n = idx & 127;
            W1Tb[n * 512 + k] = f2bf(W1[idx]);
        } else if (idx < 65536 + 6144) {
            int i2 = idx - 65536;
            int n = i2 >> 7, k = i2 & 127;
            W2Ts[i2 ^ ((n & 7) << 3)] = (n < 40) ? f2bf(W2[k * 40 + n]) : (short)0;
        } else if (idx < 65536 + 6144 + N) {
            cur[idx - 65536 - 6144] = 0;
        }
        return;
    }
    // histogram: counts must start AFTER zeroing. Blocks are not ordered, so we
    // cannot rely on prep blocks finishing first -> use a separate counts pass?
    // Safe design: histogram accumulates into cur via atomicAdd AFTER zero.
    // To keep correctness without inter-block ordering, histogram blocks spin on
    // nothing; instead we zero cur from THIS side too: each hist block zeroes a
    // disjoint slice first is racy. => Simplest safe merge: prep blocks handle
    // ONLY weights; cur zeroing moved here per-element with atomicExch? No.
    // We keep zeroing in prep blocks but make hist blocks operate on a separate
    // counts array epoch trick is overkill: instead hist uses atomicAdd on
    // cur and prep zeroes cur with plain stores -- RACE if interleaved.
    // Resolution: hist blocks process edges into cur only after checking a
    // device-scope flag is unnecessary because zeroing writes 0 and histogram
    // adds 1: if a zero lands AFTER an add, a count is lost.
    // => Do NOT merge the dependency: hist blocks here only PRELOAD edges into
    // L2 (harmless) and real histogram runs in hist2_kernel below.
    int e = (blockIdx.x - PB) * 256 + threadIdx.x;
    if (e < E) (void)erow[e];   // warm L2 for the real histogram pass
}

__global__ __launch_bounds__(256) void hist_kernel(const int* __restrict__ row,
                                                   int* __restrict__ counts, int E)
{
    int e = blockIdx.x * 256 + threadIdx.x;
    if (e < E) atomicAdd(&counts[row[e]], 1);
}

__global__ __launch_bounds__(256) void scan1_kernel(const int* __restrict__ counts,
                                                    int* __restrict__ excl,
                                                    int* __restrict__ bsum, int N)
{
    __shared__ int s[256];
    const int t = threadIdx.x;
    const int i = blockIdx.x * 256 + t;
    int v = (i < N) ? counts[i] : 0;
    s[t] = v; __syncthreads();
#pragma unroll
    for (int off = 1; off < 256; off <<= 1) {
        int tmp = (t >= off) ? s[t - off] : 0;
        __syncthreads();
        s[t] += tmp;
        __syncthreads();
    }
    if (i < N) excl[i] = s[t] - v;
    if (t == 255) bsum[blockIdx.x] = s[255];
}

// merged scan2+scan3: each block scans bsum in LDS, applies its own prefix
__global__ __launch_bounds__(256) void scan23_kernel(int* __restrict__ rowptr,
                                                     const int* __restrict__ bsum,
                                                     int* __restrict__ cur,
                                                     int N, int E, int NB)
{
    __shared__ int s[256];
    const int t = threadIdx.x;
    int v = (t < NB) ? bsum[t] : 0;
    s[t] = v; __syncthreads();
#pragma unroll
    for (int off = 1; off < 256; off <<= 1) {
        int tmp = (t >= off) ? s[t - off] : 0;
        __syncthreads();
        s[t] += tmp;
        __syncthreads();
    }
    const int add = (blockIdx.x > 0) ? s[blockIdx.x - 1] : 0;  // exclusive prefix
    const int i = blockIdx.x * 256 + t;
    if (i < N) {
        int v2 = rowptr[i] + add;
        rowptr[i] = v2;
        cur[i] = v2;
    }
    if (i == 0) rowptr[N] = E;
}

// ---------------- merged: gemm1 (blocks [0,G1)) + sortedges (blocks [G1,..)) ----------------
// gemm1: XW1b[M,128](bf16) = X[M,512](f32) @ W1. 64x128 tile, BK=64, 27.6KB LDS.
// Staging fully lane-coalesced: consecutive lanes read consecutive 16B.
__global__ __launch_bounds__(256, 5) void gemm1_sort_kernel(
    const float* __restrict__ X, const short* __restrict__ W1Tb,
    short* __restrict__ XW1b, int M, int G1,
    const int* __restrict__ erow, const int* __restrict__ ecol,
    const float* __restrict__ ew, int* __restrict__ cur,
    int2* __restrict__ se, int E)
{
    __shared__ __align__(16) short As[64 * 72];    //  9 KB (pitch 72 shorts = 144B)
    __shared__ __align__(16) short Bs[128 * 72];   // 18 KB

    const int tid = threadIdx.x;

    if (blockIdx.x >= G1) {
        // ---- sortedges body ----
        int e = (blockIdx.x - G1) * 256 + tid;
        if (e < E) {
            int r = erow[e];
            int pos = atomicAdd(&cur[r], 1);
            se[pos] = make_int2(ecol[e], __float_as_int(ew[e]));
        }
        return;
    }

    // ---- gemm1 body ----
    const int w   = tid >> 6;
    const int l   = tid & 63;
    const int l15 = l & 15;
    const int l4  = l >> 4;
    const int row0 = blockIdx.x * 64;
    const int rb   = (w & 1) * 32;
    const int cb   = (w >> 1) * 64;

    // coalesced staging indices
    const int arow = tid >> 4;               // 0..15
    const int acol = (tid & 15) * 4;         // f32 col (16B chunks)
    const int ar0 = row0 + arow,      ac0 = ar0 < M ? ar0 : M - 1;
    const int ar1 = row0 + 16 + arow, ac1 = ar1 < M ? ar1 : M - 1;
    const int ar2 = row0 + 32 + arow, ac2 = ar2 < M ? ar2 : M - 1;
    const int ar3 = row0 + 48 + arow, ac3 = ar3 < M ? ar3 : M - 1;
    const float* ap0 = X + (size_t)ac0 * 512 + acol;
    const float* ap1 = X + (size_t)ac1 * 512 + acol;
    const float* ap2 = X + (size_t)ac2 * 512 + acol;
    const float* ap3 = X + (size_t)ac3 * 512 + acol;
    const int brow = tid >> 3;               // 0..31
    const int bcol = (tid & 7) * 8;          // bf16 col (16B chunks)
    const short* bp0 = W1Tb + (size_t)(brow) * 512 + bcol;
    const short* bp1 = W1Tb + (size_t)(32 + brow) * 512 + bcol;
    const short* bp2 = W1Tb + (size_t)(64 + brow) * 512 + bcol;
    const short* bp3 = W1Tb + (size_t)(96 + brow) * 512 + bcol;

    f32x4 acc[2][4];
#pragma unroll
    for (int i = 0; i < 2; ++i)
#pragma unroll
        for (int f = 0; f < 4; ++f) acc[i][f] = (f32x4)0.f;

    // prologue loads (kt = 0)
    float4 a0 = *(const float4*)(ap0);
    float4 a1 = *(const float4*)(ap1);
    float4 a2 = *(const float4*)(ap2);
    float4 a3 = *(const float4*)(ap3);
    bf16x8 bv0 = *(const bf16x8*)(bp0);
    bf16x8 bv1 = *(const bf16x8*)(bp1);
    bf16x8 bv2 = *(const bf16x8*)(bp2);
    bf16x8 bv3 = *(const bf16x8*)(bp3);

#pragma unroll
    for (int kt = 0; kt < 8; ++kt) {
        __syncthreads();                      // previous compute done -> safe to overwrite
        *(uint2*)&As[(arow)      * 72 + acol] = cvt4(a0);
        *(uint2*)&As[(16 + arow) * 72 + acol] = cvt4(a1);
        *(uint2*)&As[(32 + arow) * 72 + acol] = cvt4(a2);
        *(uint2*)&As[(48 + arow) * 72 + acol] = cvt4(a3);
        *(bf16x8*)&Bs[(brow)      * 72 + bcol] = bv0;
        *(bf16x8*)&Bs[(32 + brow) * 72 + bcol] = bv1;
        *(bf16x8*)&Bs[(64 + brow) * 72 + bcol] = bv2;
        *(bf16x8*)&Bs[(96 + brow) * 72 + bcol] = bv3;
        __syncthreads();

        if (kt < 7) {                         // issue next-tile loads BEFORE compute
            a0 = *(const float4*)(ap0 + (kt + 1) * 64);
            a1 = *(const float4*)(ap1 + (kt + 1) * 64);
            a2 = *(const float4*)(ap2 + (kt + 1) * 64);
            a3 = *(const float4*)(ap3 + (kt + 1) * 64);
            bv0 = *(const bf16x8*)(bp0 + (kt + 1) * 64);
            bv1 = *(const bf16x8*)(bp1 + (kt + 1) * 64);
            bv2 = *(const bf16x8*)(bp2 + (kt + 1) * 64);
            bv3 = *(const bf16x8*)(bp3 + (kt + 1) * 64);
        }

#pragma unroll
        for (int kk = 0; kk < 2; ++kk) {
            bf16x8 af0 = *(const bf16x8*)&As[(rb + l15) * 72 + kk * 32 + l4 * 8];
            bf16x8 af1 = *(const bf16x8*)&As[(rb + 16 + l15) * 72 + kk * 32 + l4 * 8];
#pragma unroll
            for (int f = 0; f < 4; ++f) {
                const bf16x8 bf_ = *(const bf16x8*)&Bs[(cb + f * 16 + l15) * 72 + kk * 32 + l4 * 8];
                acc[0][f] = __builtin_amdgcn_mfma_f32_16x16x32_bf16(af0, bf_, acc[0][f], 0, 0, 0);
                acc[1][f] = __builtin_amdgcn_mfma_f32_16x16x32_bf16(af1, bf_, acc[1][f], 0, 0, 0);
            }
        }
    }

#pragma unroll
    for (int i = 0; i < 2; ++i)
#pragma unroll
        for (int r = 0; r < 4; ++r) {
            const int row = row0 + rb + i * 16 + l4 * 4 + r;
            if (row < M) {
#pragma unroll
                for (int f = 0; f < 4; ++f)
                    XW1b[(size_t)row * 128 + cb + f * 16 + l15] = f2bf(acc[i][f][r]);
            }
        }
}

// ---- fused segment1+gemm2: h48[r] = bf16(relu(b1 + Σ w_j xw1b[col_j])) @ W2 ----
__global__ __launch_bounds__(256) void seg1g2_kernel(
    const int* __restrict__ rowptr, const int2* __restrict__ se,
    const uint4* __restrict__ x4, const float* __restrict__ b1,
    const short* __restrict__ W2Ts, unsigned short* __restrict__ h48, int N)
{
    __shared__ __align__(16) short Ws[48 * 128];   // 12 KB, pre-swizzled
    __shared__ __align__(16) short Hs[16 * 136];   // 4.25 KB, pitch 136

    const int tid  = threadIdx.x;
    const int w    = tid >> 6;
    const int lane = tid & 63;
    const int qt   = lane >> 4;
    const int ql   = lane & 15;
    const int row0q = blockIdx.x * 4;
    const int r  = row0q + w;
    const int rc = r < N ? r : N - 1;     // clamp: all waves reach the barrier

    {
        const char* src = (const char*)W2Ts;
        char* dst = (char*)Ws;
#pragma unroll
        for (int i = 0; i < 3; ++i)
            gload16(src + i * 4096 + tid * 16, dst + i * 4096 + tid * 16);
    }

    float acc[8];
    if (qt == 0) {
        const float4 ba = *(const float4*)(b1 + 8 * ql);
        const float4 bb = *(const float4*)(b1 + 8 * ql + 4);
        acc[0]=ba.x; acc[1]=ba.y; acc[2]=ba.z; acc[3]=ba.w;
        acc[4]=bb.x; acc[5]=bb.y; acc[6]=bb.z; acc[7]=bb.w;
    } else {
#pragma unroll
        for (int i = 0; i < 8; ++i) acc[i] = 0.f;
    }

    int j = rowptr[rc];
    const int end = rowptr[rc + 1];
    for (; j + 7 < end; j += 8) {
        const int2 ea = se[j + qt];
        const int2 eb = se[j + 4 + qt];
        const uint4 ua = x4[(size_t)ea.x * 16 + ql];
        const uint4 ub = x4[(size_t)eb.x * 16 + ql];
        const float wa = __int_as_float(ea.y), wb = __int_as_float(eb.y);
        acc[0] = fmaf(wa, bflo(ua.x), acc[0]); acc[1] = fmaf(wa, bfhi(ua.x), acc[1]);
        acc[2] = fmaf(wa, bflo(ua.y), acc[2]); acc[3] = fmaf(wa, bfhi(ua.y), acc[3]);
        acc[4] = fmaf(wa, bflo(ua.z), acc[4]); acc[5] = fmaf(wa, bfhi(ua.z), acc[5]);
        acc[6] = fmaf(wa, bflo(ua.w), acc[6]); acc[7] = fmaf(wa, bfhi(ua.w), acc[7]);
        acc[0] = fmaf(wb, bflo(ub.x), acc[0]); acc[1] = fmaf(wb, bfhi(ub.x), acc[1]);
        acc[2] = fmaf(wb, bflo(ub.y), acc[2]); acc[3] = fmaf(wb, bfhi(ub.y), acc[3]);
        acc[4] = fmaf(wb, bflo(ub.z), acc[4]); acc[5] = fmaf(wb, bfhi(ub.z), acc[5]);
        acc[6] = fmaf(wb, bflo(ub.w), acc[6]); acc[7] = fmaf(wb, bfhi(ub.w), acc[7]);
    }
    for (; j < end; j += 4) {
        const int idx = j + qt;
        const int ic  = idx < end ? idx : end - 1;
        const int2 e  = se[ic];
        const float wt = idx < end ? __int_as_float(e.y) : 0.f;
        const uint4 u = x4[(size_t)e.x * 16 + ql];
        acc[0] = fmaf(wt, bflo(u.x), acc[0]); acc[1] = fmaf(wt, bfhi(u.x), acc[1]);
        acc[2] = fmaf(wt, bflo(u.y), acc[2]); acc[3] = fmaf(wt, bfhi(u.y), acc[3]);
        acc[4] = fmaf(wt, bflo(u.z), acc[4]); acc[5] = fmaf(wt, bfhi(u.z), acc[5]);
        acc[6] = fmaf(wt, bflo(u.w), acc[6]); acc[7] = fmaf(wt, bfhi(u.w), acc[7]);
    }
#pragma unroll
    for (int i = 0; i < 8; ++i) {
        acc[i] += __shfl_xor(acc[i], 16);
        acc[i] += __shfl_xor(acc[i], 32);
    }
    if (qt == 0) {
        uint4 o;
        o.x = pack2bf(fmaxf(acc[0], 0.f), fmaxf(acc[1], 0.f));
        o.y = pack2bf(fmaxf(acc[2], 0.f), fmaxf(acc[3], 0.f));
        o.z = pack2bf(fmaxf(acc[4], 0.f), fmaxf(acc[5], 0.f));
        o.w = pack2bf(fmaxf(acc[6], 0.f), fmaxf(acc[7], 0.f));
        *(uint4*)&Hs[w * 136 + ql * 8] = o;   // h row w (relu'd bf16)
    }
    __syncthreads();   // drains gload16 (vmcnt) + Hs writes

    // MFMA tail on wave 0: D[16,48] = Hs[16,128] @ W2; rows 4..15 garbage, discarded.
    if (tid < 64) {
        const int l15 = lane & 15;
        const int l4  = lane >> 4;
        const int swz = (l15 & 7) << 3;
        f32x4 acc2[3];
#pragma unroll
        for (int f = 0; f < 3; ++f) acc2[f] = (f32x4)0.f;
#pragma unroll
        for (int kt = 0; kt < 4; ++kt) {
            const bf16x8 a = *(const bf16x8*)&Hs[l15 * 136 + kt * 32 + l4 * 8];
#pragma unroll
            for (int f = 0; f < 3; ++f) {
                const int si = ((f * 16 + l15) * 128 + kt * 32 + l4 * 8) ^ swz;
                const bf16x8 b = *(const bf16x8*)&Ws[si];
                acc2[f] = __builtin_amdgcn_mfma_f32_16x16x32_bf16(a, b, acc2[f], 0, 0, 0);
            }
        }
        if (l4 == 0) {
#pragma unroll
            for (int rr = 0; rr < 4; ++rr) {
                const int grow = row0q + rr;
                if (grow < N) {
#pragma unroll
                    for (int f = 0; f < 3; ++f)
                        h48[(size_t)grow * 48 + f * 16 + l15] =
                            (unsigned short)f2bf(acc2[f][rr]);
                }
            }
        }
    }
}

// ---- segment2: out[r] = b2 + sum_j w_j * h48[col_j]  (quarter-wave, 4 edges/instr) ----
__global__ __launch_bounds__(256) void segment2_kernel(
    const int* __restrict__ rowptr, const int2* __restrict__ se,
    const uint2* __restrict__ h48, const float* __restrict__ b2,
    float* __restrict__ out, int N)
{
    const int w    = threadIdx.x >> 6;
    const int lane = threadIdx.x & 63;
    const int qt   = lane >> 4;
    const int ql   = lane & 15;
    const int r = blockIdx.x * 4 + w;
    if (r >= N) return;

    float acc[4];
    if (qt == 0 && ql < 10) {
        const float4 bb = *(const float4*)(b2 + 4 * ql);
        acc[0]=bb.x; acc[1]=bb.y; acc[2]=bb.z; acc[3]=bb.w;
    } else {
#pragma unroll
        for (int i = 0; i < 4; ++i) acc[i] = 0.f;
    }

    int j = rowptr[r];
    const int end = rowptr[r + 1];
    for (; j + 7 < end; j += 8) {
        const int2 ea = se[j + qt];
        const int2 eb = se[j + 4 + qt];
        const uint2 ua = h48[(size_t)ea.x * 12 + ql];
        const uint2 ub = h48[(size_t)eb.x * 12 + ql];
        const float wa = __int_as_float(ea.y), wb = __int_as_float(eb.y);
        acc[0] = fmaf(wa, bflo(ua.x), acc[0]); acc[1] = fmaf(wa, bfhi(ua.x), acc[1]);
        acc[2] = fmaf(wa, bflo(ua.y), acc[2]); acc[3] = fmaf(wa, bfhi(ua.y), acc[3]);
        acc[0] = fmaf(wb, bflo(ub.x), acc[0]); acc[1] = fmaf(wb, bfhi(ub.x), acc[1]);
        acc[2] = fmaf(wb, bflo(ub.y), acc[2]); acc[3] = fmaf(wb, bfhi(ub.y), acc[3]);
    }
    for (; j < end; j += 4) {
        const int idx = j + qt;
        const int ic  = idx < end ? idx : end - 1;
        const int2 e  = se[ic];
        const float wt = idx < end ? __int_as_float(e.y) : 0.f;
        const uint2 u = h48[(size_t)e.x * 12 + ql];
        acc[0] = fmaf(wt, bflo(u.x), acc[0]); acc[1] = fmaf(wt, bfhi(u.x), acc[1]);
        acc[2] = fmaf(wt, bflo(u.y), acc[2]); acc[3] = fmaf(wt, bfhi(u.y), acc[3]);
    }
#pragma unroll
    for (int i = 0; i < 4; ++i) {
        acc[i] += __shfl_xor(acc[i], 16);
        acc[i] += __shfl_xor(acc[i], 32);
    }
    if (qt == 0 && ql < 10) {
        float4 o; o.x = acc[0]; o.y = acc[1]; o.z = acc[2]; o.w = acc[3];
        *(float4*)(out + (size_t)r * 40 + 4 * ql) = o;
    }
}

extern "C" void kernel_launch(void* const* d_in, const int* in_sizes, int n_in,
                              void* d_out, int out_size, void* d_ws, size_t ws_size,
                              hipStream_t stream)
{
    const float* x  = (const float*)d_in[0];
    const int* erow = (const int*)d_in[1];
    const int* ecol = (const int*)d_in[2];
    const float* ew = (const float*)d_in[3];
    const float* w1 = (const float*)d_in[4];
    const float* b1 = (const float*)d_in[5];
    const float* w2 = (const float*)d_in[6];
    const float* b2 = (const float*)d_in[7];
    float* out = (float*)d_out;

    const int N = in_sizes[0] / 512;   // 50000
    const int E = in_sizes[1];         // 800000
    const int NB = (N + 255) / 256;    // 196 (<=256 for scan23)

    // workspace layout (16B-aligned segments)
    short* w1tb = (short*)d_ws;                      // 128*512 bf16 (plain W1T)
    short* w2ts = w1tb + 65536;                      // 48*128 bf16 (swizzled)
    short* xw1b = w2ts + 8192;                       // N*128 bf16 (gather table L1)
    short* h48  = xw1b + (size_t)N * 128;            // N*48 bf16 (gather table L2)
    int* rowptr = (int*)(h48 + (size_t)N * 128);     // N+1 (h48 slot padded to N*128)
    int* cur    = rowptr + (N + 1);                  // N
    int* bsum   = cur + N;                           // 256 (+pad to 8B align)
    int2* se    = (int2*)(bsum + 256 + ((N + 1) & 1)); // E packed edges

    // weight prep + cur zero (+ L2 warm of erow), then CSR build
    const int PB = (65536 + 6144 + N + 255) / 256;
    prep_hist_kernel<<<PB + (E + 255) / 256, 256, 0, stream>>>(
        w1, w1tb, w2, w2ts, cur, N, PB, erow, E);
    hist_kernel<<<(E + 255) / 256, 256, 0, stream>>>(erow, cur, E);
    scan1_kernel<<<NB, 256, 0, stream>>>(cur, rowptr, bsum, N);
    scan23_kernel<<<NB, 256, 0, stream>>>(rowptr, bsum, cur, N, E, NB);

    // gemm1 + sortedges (independent, merged)
    const int G1 = (N + 63) / 64;
    const int GS = (E + 255) / 256;
    gemm1_sort_kernel<<<G1 + GS, 256, 0, stream>>>(x, w1tb, xw1b, N, G1,
                                                   erow, ecol, ew, cur, se, E);

    // layer 1 aggregate + layer 2 GEMM (fused)
    seg1g2_kernel<<<(N + 3) / 4, 256, 0, stream>>>(rowptr, se,
                                                   (const uint4*)xw1b, b1,
                                                   w2ts, (unsigned short*)h48, N);

    // layer 2 aggregate
    segment2_kernel<<<(N + 3) / 4, 256, 0, stream>>>(rowptr, se,
                                                     (const uint2*)h48, b2, out, N);
}

// Round 19
// 155.233 us; speedup vs baseline: 1.0508x; 1.0264x over previous
//
#include <hip/hip_runtime.h>
#include <hip/hip_bf16.h>
#include <cstddef>

// GCN forward: out = A·(relu(A·(X·W1)+b1))·W2 + b2
// NFEAT=512, NHID=128, NCLS=40 hard-wired; N,E from in_sizes.
// R19 = R14 byte-exact revert (best measured: 155.5 us).
// 7 launches. sortedges+gemm1 merged; gemm2 fused into segment1; scan2+scan3 merged.

typedef float f32x4 __attribute__((ext_vector_type(4)));
typedef short bf16x8 __attribute__((ext_vector_type(8)));

static __device__ __forceinline__ short f2bf(float f) {
    __hip_bfloat16 b = __float2bfloat16(f);
    return *reinterpret_cast<short*>(&b);
}
static __device__ __forceinline__ float bflo(unsigned u) {
    union { unsigned i; float f; } v; v.i = u << 16; return v.f;
}
static __device__ __forceinline__ float bfhi(unsigned u) {
    union { unsigned i; float f; } v; v.i = u & 0xFFFF0000u; return v.f;
}
static __device__ __forceinline__ unsigned pack2bf(float lo, float hi) {
    unsigned a = (unsigned short)f2bf(lo);
    unsigned b = (unsigned short)f2bf(hi);
    return a | (b << 16);
}

typedef const __attribute__((address_space(1))) void* gas_ptr;
typedef __attribute__((address_space(3))) void* las_ptr;
static __device__ __forceinline__ void gload16(const void* g, void* l) {
    __builtin_amdgcn_global_load_lds((gas_ptr)g, (las_ptr)l, 16, 0, 0);
}

// ---- prep: W1->W1Tb (plain bf16 W1T [128][512]), W2->W2Ts (swizzled), zero cur ----
__global__ __launch_bounds__(256) void prep_kernel(
    const float* __restrict__ W1, short* __restrict__ W1Tb,
    const float* __restrict__ W2, short* __restrict__ W2Ts,
    int* __restrict__ cur, int N)
{
    int idx = blockIdx.x * 256 + threadIdx.x;
    if (idx < 65536) {
        int k = idx >> 7, n = idx & 127;
        W1Tb[n * 512 + k] = f2bf(W1[idx]);
    } else if (idx < 65536 + 6144) {
        int i2 = idx - 65536;
        int n = i2 >> 7, k = i2 & 127;
        W2Ts[i2 ^ ((n & 7) << 3)] = (n < 40) ? f2bf(W2[k * 40 + n]) : (short)0;
    } else if (idx < 65536 + 6144 + N) {
        cur[idx - 65536 - 6144] = 0;
    }
}

// ---------------- CSR build ----------------
__global__ __launch_bounds__(256) void hist_kernel(const int* __restrict__ row,
                                                   int* __restrict__ counts, int E)
{
    int e = blockIdx.x * 256 + threadIdx.x;
    if (e < E) atomicAdd(&counts[row[e]], 1);
}

__global__ __launch_bounds__(256) void scan1_kernel(const int* __restrict__ counts,
                                                    int* __restrict__ excl,
                                                    int* __restrict__ bsum, int N)
{
    __shared__ int s[256];
    const int t = threadIdx.x;
    const int i = blockIdx.x * 256 + t;
    int v = (i < N) ? counts[i] : 0;
    s[t] = v; __syncthreads();
#pragma unroll
    for (int off = 1; off < 256; off <<= 1) {
        int tmp = (t >= off) ? s[t - off] : 0;
        __syncthreads();
        s[t] += tmp;
        __syncthreads();
    }
    if (i < N) excl[i] = s[t] - v;
    if (t == 255) bsum[blockIdx.x] = s[255];
}

// merged scan2+scan3: each block scans bsum in LDS, applies its own prefix
__global__ __launch_bounds__(256) void scan23_kernel(int* __restrict__ rowptr,
                                                     const int* __restrict__ bsum,
                                                     int* __restrict__ cur,
                                                     int N, int E, int NB)
{
    __shared__ int s[256];
    const int t = threadIdx.x;
    int v = (t < NB) ? bsum[t] : 0;
    s[t] = v; __syncthreads();
#pragma unroll
    for (int off = 1; off < 256; off <<= 1) {
        int tmp = (t >= off) ? s[t - off] : 0;
        __syncthreads();
        s[t] += tmp;
        __syncthreads();
    }
    const int add = (blockIdx.x > 0) ? s[blockIdx.x - 1] : 0;  // exclusive prefix
    const int i = blockIdx.x * 256 + t;
    if (i < N) {
        int v2 = rowptr[i] + add;
        rowptr[i] = v2;
        cur[i] = v2;
    }
    if (i == 0) rowptr[N] = E;
}

// ---------------- merged: gemm1 (blocks [0,G1)) + sortedges (blocks [G1,..)) ----------------
// gemm1: XW1b[M,128](bf16) = X[M,512](f32) @ W1. 64x128 tile, BK=32, 15KB LDS.
__global__ __launch_bounds__(256, 6) void gemm1_sort_kernel(
    const float* __restrict__ X, const short* __restrict__ W1Tb,
    short* __restrict__ XW1b, int M, int G1,
    const int* __restrict__ erow, const int* __restrict__ ecol,
    const float* __restrict__ ew, int* __restrict__ cur,
    int2* __restrict__ se, int E)
{
    __shared__ __align__(16) short As[64 * 40];
    __shared__ __align__(16) short Bs[128 * 40];

    const int tid = threadIdx.x;

    if (blockIdx.x >= G1) {
        // ---- sortedges body ----
        int e = (blockIdx.x - G1) * 256 + tid;
        if (e < E) {
            int r = erow[e];
            int pos = atomicAdd(&cur[r], 1);
            se[pos] = make_int2(ecol[e], __float_as_int(ew[e]));
        }
        return;
    }

    // ---- gemm1 body ----
    const int w   = tid >> 6;
    const int l   = tid & 63;
    const int l15 = l & 15;
    const int l4  = l >> 4;
    const int row0 = blockIdx.x * 64;
    const int rb   = (w & 1) * 32;
    const int cb   = (w >> 1) * 64;

    const int sr = tid >> 2;
    const int sc = (tid & 3) * 8;
    const int ga = row0 + sr < M ? row0 + sr : M - 1;
    const float* ax = X + (size_t)ga * 512 + sc;
    const int bn = tid >> 1;
    const int bk = (tid & 1) * 16;
    const short* bw = W1Tb + (size_t)bn * 512 + bk;

    f32x4 acc[2][4];
#pragma unroll
    for (int i = 0; i < 2; ++i)
#pragma unroll
        for (int f = 0; f < 4; ++f) acc[i][f] = (f32x4)0.f;

    float4 a0 = *(const float4*)(ax);
    float4 a1 = *(const float4*)(ax + 4);
    bf16x8 bv0 = *(const bf16x8*)(bw);
    bf16x8 bv1 = *(const bf16x8*)(bw + 8);

#pragma unroll
    for (int kt = 0; kt < 16; ++kt) {
        __syncthreads();
        bf16x8 av;
        av[0]=f2bf(a0.x); av[1]=f2bf(a0.y); av[2]=f2bf(a0.z); av[3]=f2bf(a0.w);
        av[4]=f2bf(a1.x); av[5]=f2bf(a1.y); av[6]=f2bf(a1.z); av[7]=f2bf(a1.w);
        *(bf16x8*)&As[sr * 40 + sc] = av;
        *(bf16x8*)&Bs[bn * 40 + bk] = bv0;
        *(bf16x8*)&Bs[bn * 40 + bk + 8] = bv1;
        __syncthreads();

        if (kt < 15) {
            a0 = *(const float4*)(ax + (kt + 1) * 32);
            a1 = *(const float4*)(ax + (kt + 1) * 32 + 4);
            bv0 = *(const bf16x8*)(bw + (kt + 1) * 32);
            bv1 = *(const bf16x8*)(bw + (kt + 1) * 32 + 8);
        }

        bf16x8 af0 = *(const bf16x8*)&As[(rb + l15) * 40 + l4 * 8];
        bf16x8 af1 = *(const bf16x8*)&As[(rb + 16 + l15) * 40 + l4 * 8];
#pragma unroll
        for (int f = 0; f < 4; ++f) {
            const bf16x8 bf_ = *(const bf16x8*)&Bs[(cb + f * 16 + l15) * 40 + l4 * 8];
            acc[0][f] = __builtin_amdgcn_mfma_f32_16x16x32_bf16(af0, bf_, acc[0][f], 0, 0, 0);
            acc[1][f] = __builtin_amdgcn_mfma_f32_16x16x32_bf16(af1, bf_, acc[1][f], 0, 0, 0);
        }
    }

#pragma unroll
    for (int i = 0; i < 2; ++i)
#pragma unroll
        for (int r = 0; r < 4; ++r) {
            const int row = row0 + rb + i * 16 + l4 * 4 + r;
            if (row < M) {
#pragma unroll
                for (int f = 0; f < 4; ++f)
                    XW1b[(size_t)row * 128 + cb + f * 16 + l15] = f2bf(acc[i][f][r]);
            }
        }
}

// ---- fused segment1+gemm2: h48[r] = bf16(relu(b1 + Σ w_j xw1b[col_j])) @ W2 ----
// Gather: quarter-wave (4 edges/instr, x2 unroll). Tail: h rows -> LDS, 12 MFMA.
__global__ __launch_bounds__(256) void seg1g2_kernel(
    const int* __restrict__ rowptr, const int2* __restrict__ se,
    const uint4* __restrict__ x4, const float* __restrict__ b1,
    const short* __restrict__ W2Ts, unsigned short* __restrict__ h48, int N)
{
    __shared__ __align__(16) short Ws[48 * 128];   // 12 KB, pre-swizzled
    __shared__ __align__(16) short Hs[16 * 136];   // 4.25 KB, pitch 136 (2-way free)

    const int tid  = threadIdx.x;
    const int w    = tid >> 6;
    const int lane = tid & 63;
    const int qt   = lane >> 4;
    const int ql   = lane & 15;
    const int row0q = blockIdx.x * 4;
    const int r  = row0q + w;
    const int rc = r < N ? r : N - 1;     // clamp: all waves reach the barrier

    // stage W2 into LDS (async; drained by the barrier below)
    {
        const char* src = (const char*)W2Ts;
        char* dst = (char*)Ws;
#pragma unroll
        for (int i = 0; i < 3; ++i)
            gload16(src + i * 4096 + tid * 16, dst + i * 4096 + tid * 16);
    }

    float acc[8];
    if (qt == 0) {
        const float4 ba = *(const float4*)(b1 + 8 * ql);
        const float4 bb = *(const float4*)(b1 + 8 * ql + 4);
        acc[0]=ba.x; acc[1]=ba.y; acc[2]=ba.z; acc[3]=ba.w;
        acc[4]=bb.x; acc[5]=bb.y; acc[6]=bb.z; acc[7]=bb.w;
    } else {
#pragma unroll
        for (int i = 0; i < 8; ++i) acc[i] = 0.f;
    }

    int j = rowptr[rc];
    const int end = rowptr[rc + 1];
    for (; j + 7 < end; j += 8) {
        const int2 ea = se[j + qt];
        const int2 eb = se[j + 4 + qt];
        const uint4 ua = x4[(size_t)ea.x * 16 + ql];
        const uint4 ub = x4[(size_t)eb.x * 16 + ql];
        const float wa = __int_as_float(ea.y), wb = __int_as_float(eb.y);
        acc[0] = fmaf(wa, bflo(ua.x), acc[0]); acc[1] = fmaf(wa, bfhi(ua.x), acc[1]);
        acc[2] = fmaf(wa, bflo(ua.y), acc[2]); acc[3] = fmaf(wa, bfhi(ua.y), acc[3]);
        acc[4] = fmaf(wa, bflo(ua.z), acc[4]); acc[5] = fmaf(wa, bfhi(ua.z), acc[5]);
        acc[6] = fmaf(wa, bflo(ua.w), acc[6]); acc[7] = fmaf(wa, bfhi(ua.w), acc[7]);
        acc[0] = fmaf(wb, bflo(ub.x), acc[0]); acc[1] = fmaf(wb, bfhi(ub.x), acc[1]);
        acc[2] = fmaf(wb, bflo(ub.y), acc[2]); acc[3] = fmaf(wb, bfhi(ub.y), acc[3]);
        acc[4] = fmaf(wb, bflo(ub.z), acc[4]); acc[5] = fmaf(wb, bfhi(ub.z), acc[5]);
        acc[6] = fmaf(wb, bflo(ub.w), acc[6]); acc[7] = fmaf(wb, bfhi(ub.w), acc[7]);
    }
    for (; j < end; j += 4) {
        const int idx = j + qt;
        const int ic  = idx < end ? idx : end - 1;
        const int2 e  = se[ic];
        const float wt = idx < end ? __int_as_float(e.y) : 0.f;
        const uint4 u = x4[(size_t)e.x * 16 + ql];
        acc[0] = fmaf(wt, bflo(u.x), acc[0]); acc[1] = fmaf(wt, bfhi(u.x), acc[1]);
        acc[2] = fmaf(wt, bflo(u.y), acc[2]); acc[3] = fmaf(wt, bfhi(u.y), acc[3]);
        acc[4] = fmaf(wt, bflo(u.z), acc[4]); acc[5] = fmaf(wt, bfhi(u.z), acc[5]);
        acc[6] = fmaf(wt, bflo(u.w), acc[6]); acc[7] = fmaf(wt, bfhi(u.w), acc[7]);
    }
#pragma unroll
    for (int i = 0; i < 8; ++i) {
        acc[i] += __shfl_xor(acc[i], 16);
        acc[i] += __shfl_xor(acc[i], 32);
    }
    if (qt == 0) {
        uint4 o;
        o.x = pack2bf(fmaxf(acc[0], 0.f), fmaxf(acc[1], 0.f));
        o.y = pack2bf(fmaxf(acc[2], 0.f), fmaxf(acc[3], 0.f));
        o.z = pack2bf(fmaxf(acc[4], 0.f), fmaxf(acc[5], 0.f));
        o.w = pack2bf(fmaxf(acc[6], 0.f), fmaxf(acc[7], 0.f));
        *(uint4*)&Hs[w * 136 + ql * 8] = o;   // h row w (relu'd bf16)
    }
    __syncthreads();   // drains gload16 (vmcnt) + Hs writes

    // MFMA tail on wave 0: D[16,48] = Hs[16,128] @ W2; rows 4..15 garbage, discarded.
    if (tid < 64) {
        const int l15 = lane & 15;
        const int l4  = lane >> 4;
        const int swz = (l15 & 7) << 3;
        f32x4 acc2[3];
#pragma unroll
        for (int f = 0; f < 3; ++f) acc2[f] = (f32x4)0.f;
#pragma unroll
        for (int kt = 0; kt < 4; ++kt) {
            const bf16x8 a = *(const bf16x8*)&Hs[l15 * 136 + kt * 32 + l4 * 8];
#pragma unroll
            for (int f = 0; f < 3; ++f) {
                const int si = ((f * 16 + l15) * 128 + kt * 32 + l4 * 8) ^ swz;
                const bf16x8 b = *(const bf16x8*)&Ws[si];
                acc2[f] = __builtin_amdgcn_mfma_f32_16x16x32_bf16(a, b, acc2[f], 0, 0, 0);
            }
        }
        if (l4 == 0) {     // D rows 0..3 live in lanes 0..15, regs 0..3
#pragma unroll
            for (int rr = 0; rr < 4; ++rr) {
                const int grow = row0q + rr;
                if (grow < N) {
#pragma unroll
                    for (int f = 0; f < 3; ++f)
                        h48[(size_t)grow * 48 + f * 16 + l15] =
                            (unsigned short)f2bf(acc2[f][rr]);
                }
            }
        }
    }
}

// ---- segment2: out[r] = b2 + sum_j w_j * h48[col_j]  (quarter-wave, 4 edges/instr) ----
__global__ __launch_bounds__(256) void segment2_kernel(
    const int* __restrict__ rowptr, const int2* __restrict__ se,
    const uint2* __restrict__ h48, const float* __restrict__ b2,
    float* __restrict__ out, int N)
{
    const int w    = threadIdx.x >> 6;
    const int lane = threadIdx.x & 63;
    const int qt   = lane >> 4;
    const int ql   = lane & 15;
    const int r = blockIdx.x * 4 + w;
    if (r >= N) return;

    float acc[4];
    if (qt == 0 && ql < 10) {
        const float4 bb = *(const float4*)(b2 + 4 * ql);
        acc[0]=bb.x; acc[1]=bb.y; acc[2]=bb.z; acc[3]=bb.w;
    } else {
#pragma unroll
        for (int i = 0; i < 4; ++i) acc[i] = 0.f;
    }

    int j = rowptr[r];
    const int end = rowptr[r + 1];
    for (; j + 7 < end; j += 8) {
        const int2 ea = se[j + qt];
        const int2 eb = se[j + 4 + qt];
        const uint2 ua = h48[(size_t)ea.x * 12 + ql];
        const uint2 ub = h48[(size_t)eb.x * 12 + ql];
        const float wa = __int_as_float(ea.y), wb = __int_as_float(eb.y);
        acc[0] = fmaf(wa, bflo(ua.x), acc[0]); acc[1] = fmaf(wa, bfhi(ua.x), acc[1]);
        acc[2] = fmaf(wa, bflo(ua.y), acc[2]); acc[3] = fmaf(wa, bfhi(ua.y), acc[3]);
        acc[0] = fmaf(wb, bflo(ub.x), acc[0]); acc[1] = fmaf(wb, bfhi(ub.x), acc[1]);
        acc[2] = fmaf(wb, bflo(ub.y), acc[2]); acc[3] = fmaf(wb, bfhi(ub.y), acc[3]);
    }
    for (; j < end; j += 4) {
        const int idx = j + qt;
        const int ic  = idx < end ? idx : end - 1;
        const int2 e  = se[ic];
        const float wt = idx < end ? __int_as_float(e.y) : 0.f;
        const uint2 u = h48[(size_t)e.x * 12 + ql];
        acc[0] = fmaf(wt, bflo(u.x), acc[0]); acc[1] = fmaf(wt, bfhi(u.x), acc[1]);
        acc[2] = fmaf(wt, bflo(u.y), acc[2]); acc[3] = fmaf(wt, bfhi(u.y), acc[3]);
    }
#pragma unroll
    for (int i = 0; i < 4; ++i) {
        acc[i] += __shfl_xor(acc[i], 16);
        acc[i] += __shfl_xor(acc[i], 32);
    }
    if (qt == 0 && ql < 10) {
        float4 o; o.x = acc[0]; o.y = acc[1]; o.z = acc[2]; o.w = acc[3];
        *(float4*)(out + (size_t)r * 40 + 4 * ql) = o;
    }
}

extern "C" void kernel_launch(void* const* d_in, const int* in_sizes, int n_in,
                              void* d_out, int out_size, void* d_ws, size_t ws_size,
                              hipStream_t stream)
{
    const float* x  = (const float*)d_in[0];
    const int* erow = (const int*)d_in[1];
    const int* ecol = (const int*)d_in[2];
    const float* ew = (const float*)d_in[3];
    const float* w1 = (const float*)d_in[4];
    const float* b1 = (const float*)d_in[5];
    const float* w2 = (const float*)d_in[6];
    const float* b2 = (const float*)d_in[7];
    float* out = (float*)d_out;

    const int N = in_sizes[0] / 512;   // 50000
    const int E = in_sizes[1];         // 800000
    const int NB = (N + 255) / 256;    // 196 (<=256 for scan23)

    // workspace layout (16B-aligned segments)
    short* w1tb = (short*)d_ws;                      // 128*512 bf16 (plain W1T)
    short* w2ts = w1tb + 65536;                      // 48*128 bf16 (swizzled)
    short* xw1b = w2ts + 8192;                       // N*128 bf16 (gather table L1)
    short* h48  = xw1b + (size_t)N * 128;            // N*48 bf16 (gather table L2)
    int* rowptr = (int*)(h48 + (size_t)N * 128);     // N+1 (h48 slot padded to N*128)
    int* cur    = rowptr + (N + 1);                  // N
    int* bsum   = cur + N;                           // 256 (+pad to 8B align)
    int2* se    = (int2*)(bsum + 256 + ((N + 1) & 1)); // E packed edges

    // CSR build + weight prep
    prep_kernel<<<(65536 + 6144 + N + 255) / 256, 256, 0, stream>>>(w1, w1tb, w2, w2ts, cur, N);
    hist_kernel<<<(E + 255) / 256, 256, 0, stream>>>(erow, cur, E);
    scan1_kernel<<<NB, 256, 0, stream>>>(cur, rowptr, bsum, N);
    scan23_kernel<<<NB, 256, 0, stream>>>(rowptr, bsum, cur, N, E, NB);

    // gemm1 + sortedges (independent, merged)
    const int G1 = (N + 63) / 64;
    const int GS = (E + 255) / 256;
    gemm1_sort_kernel<<<G1 + GS, 256, 0, stream>>>(x, w1tb, xw1b, N, G1,
                                                   erow, ecol, ew, cur, se, E);

    // layer 1 aggregate + layer 2 GEMM (fused)
    seg1g2_kernel<<<(N + 3) / 4, 256, 0, stream>>>(rowptr, se,
                                                   (const uint4*)xw1b, b1,
                                                   w2ts, (unsigned short*)h48, N);

    // layer 2 aggregate
    segment2_kernel<<<(N + 3) / 4, 256, 0, stream>>>(rowptr, se,
                                                     (const uint2*)h48, b2, out, N);
}